// Round 8
// baseline (279.702 us; speedup 1.0000x reference)
//
#include <hip/hip_runtime.h>

// ---------------------------------------------------------------------------
// MatchNet: 3-layer MLP (relu after every layer) -> batched PDHG LP solve.
// Shapes: X[2048,64], W1[64,1024], W2[1024,1024], W3[1024,512], S[64,512].
// Output: x [2048,512] fp32.
//
// R23: row-local MEGAKERNEL. The whole pipeline is row-parallel (H1/H2/Zb/x
// rows b..b+8 depend only on X rows b..b+8 + weights), so one kernel of 256
// blocks x 8 rows runs gemm1 -> gemm2 -> gemm3 -> pdhg with NO grid barriers
// (unlike R21's deadlocked spin-barrier design).
//  - H1,H2 in LDS f16 (stride 1032: rows land on distinct 16B bank slots).
//  - Zb never materializes: G3 accumulators == pdhg z (frag layout maps
//    exactly onto pdhg's (p,q,lm) ownership via the lm&7 row-dup trick).
//  - B-frags stream direct-to-register from W*t with 1-step prefetch;
//    weights are L2-resident (3.1 MB < 4 MB/XCD).
//  - identical cast/accumulation order everywhere -> bit-identical output.
// Launches: prep (transposes + S-frags + power_64) + mega = 2 (was 5).
// Evidence: R20/R22 incremental db/fusion attacks on the 112us "rest" all
// regressed; rest is launch/tail/roundtrip overhead this removes wholesale.
// ---------------------------------------------------------------------------

typedef _Float16 half8 __attribute__((ext_vector_type(8)));
typedef __fp16 fp16x2 __attribute__((ext_vector_type(2)));
typedef __fp16 fp16x4 __attribute__((ext_vector_type(4)));
typedef float floatx4 __attribute__((ext_vector_type(4)));

#define BATCH 2048
#define NITERS 60
#define XBS 520   // delta-xbar LDS row stride in halves
#define YLS 72    // delta-ylo  LDS row stride in halves
#define H1S 1032  // H1/H2 LDS row stride in halves (2064B: rows hit distinct 16B slots)

// ---- cross-lane sums: DPP (VALU pipe) within 16-lane rows ----
template <int CTRL>
__device__ __forceinline__ float dpp_addf(float x) {
    int y = __builtin_amdgcn_update_dpp(0, __builtin_bit_cast(int, x), CTRL, 0xf, 0xf, true);
    return x + __builtin_bit_cast(float, y);
}
__device__ __forceinline__ float sum16(float x) {
    x = dpp_addf<0xB1>(x);    // quad_perm(1,0,3,2): xor 1
    x = dpp_addf<0x4E>(x);    // quad_perm(2,3,0,1): xor 2
    x = dpp_addf<0x124>(x);   // row_ror:4
    x = dpp_addf<0x128>(x);   // row_ror:8 -> full 16-lane sum in all lanes
    return x;
}
__device__ __forceinline__ float sum64(float x) {
    x = sum16(x);
    x += __builtin_bit_cast(float, __builtin_amdgcn_ds_swizzle(__builtin_bit_cast(int, x), 0x401F)); // xor16
    x += __shfl_xor(x, 32, 64);   // cross-half combine
    return x;
}

// ---------------- 64-dim power iteration for tau (one 256-thread block) --------
// Exact reduction of the reference 512-dim recursion: w_k = S v_k;
//   n_k = sqrt(w'Gw + 2|w|^2 + 1);  w_{k+1} = (Gw + w)/n_k;
//   w_0[i] = rowcount_i / sqrt(512);  L = sqrt(|w_30|^2 + 1);  tau = 0.9/L.
__device__ void power_64(const float* __restrict__ S, float* __restrict__ tau_g) {
    __shared__ unsigned long long rowm[64][8];   // row bitmasks of S
    __shared__ float G[64][65];                  // Gram, +1 pad (conflict-free)
    __shared__ float wl[64], pg[4][64];
    int t = threadIdx.x, wv = t >> 6, ln = t & 63;
    for (int rr = 0; rr < 16; rr++) {
        int r = wv * 16 + rr;
        float v[8];
#pragma unroll
        for (int e = 0; e < 8; e++) v[e] = S[r * 512 + e * 64 + ln];
#pragma unroll
        for (int e = 0; e < 8; e++) {
            unsigned long long m = __ballot(v[e] != 0.f);
            if (ln == 0) rowm[r][e] = m;
        }
    }
    __syncthreads();
    for (int k = 0; k < 16; k++) {
        int idx = t * 16 + k;
        int i = idx >> 6, j = idx & 63;
        int cnt = 0;
#pragma unroll
        for (int e = 0; e < 8; e++) cnt += __popcll(rowm[i][e] & rowm[j][e]);
        G[i][j] = (float)cnt;
    }
    if (wv == 0) {   // w0 = S v0 = rowcount/sqrt(512)
        int cnt = 0;
#pragma unroll
        for (int e = 0; e < 8; e++) cnt += __popcll(rowm[ln][e]);
        wl[ln] = (float)cnt * 0.044194173824159216f;
    }
    __syncthreads();
    for (int s = 0; s < 30; s++) {
        float a = 0.f;
#pragma unroll
        for (int jj = 0; jj < 16; jj++) {
            int j = wv * 16 + jj;
            a += G[ln][j] * wl[j];
        }
        pg[wv][ln] = a;
        __syncthreads();
        if (wv == 0) {
            float g = (pg[0][ln] + pg[1][ln]) + (pg[2][ln] + pg[3][ln]);  // (Gw)[ln]
            float wi = wl[ln];
            float s1 = sum64(wi * g);    // w'Gw
            float s2 = sum64(wi * wi);   // |w|^2
            float n = sqrtf(s1 + 2.f * s2 + 1.f);
            wl[ln] = (g + wi) / n;
        }
        __syncthreads();
    }
    if (wv == 0) {
        float wi = wl[ln];
        float s2 = sum64(wi * wi);
        if (ln == 0) tau_g[0] = 0.9f / sqrtf(s2 + 1.f);
    }
}

// ---------------- prep: W transposes, S frags, power_64 ------------------------
__global__ __launch_bounds__(256) void prep(
    const float* __restrict__ W1, _Float16* __restrict__ W1t,
    const float* __restrict__ W2, _Float16* __restrict__ W2t,
    const float* __restrict__ W3, _Float16* __restrict__ W3t,
    const float* __restrict__ S, _Float16* __restrict__ s1f,
    _Float16* __restrict__ s2f, float* __restrict__ tau_g) {
    __shared__ float tile[32][33];
    int tid = threadIdx.x;
    int bid = blockIdx.x;
    if (bid < 1600) {   // transpose+cast W[K][N] -> Wt[N][K]
        const float* W; _Float16* Wt; int K, N, b;
        if (bid < 64)        { W = W1; Wt = W1t; K = 64;   N = 1024; b = bid; }
        else if (bid < 1088) { W = W2; Wt = W2t; K = 1024; N = 1024; b = bid - 64; }
        else                 { W = W3; Wt = W3t; K = 1024; N = 512;  b = bid - 1088; }
        int nbx = N / 32;
        int n0 = (b % nbx) * 32, k0 = (b / nbx) * 32;
        int tx = tid & 31, ty = tid >> 5;
#pragma unroll
        for (int i = 0; i < 4; i++)
            tile[ty + i * 8][tx] = W[(size_t)(k0 + ty + i * 8) * N + n0 + tx];
        __syncthreads();
#pragma unroll
        for (int i = 0; i < 4; i++)
            Wt[(size_t)(n0 + ty + i * 8) * K + k0 + tx] = (_Float16)tile[tx][ty + i * 8];
        return;
    }
    if (bid < 1856) {
        int i = (bid - 1600) * 256 + tid;   // 0 .. 65535
        if (i < 4 * 16 * 64 * 8) {     // s1f: B-frag of S^T, k-axis in pi'-order
            int j = i & 7, lane = (i >> 3) & 63, kk = (i >> 9) & 15, wc = i >> 13;
            int pos = kk * 32 + (lane >> 4) * 8 + j;   // storage k position 0..511
            int pp = pos >> 7, r = pos & 127;
            int hh = r >> 6, r2 = r & 63;
            int lmc = r2 >> 2, t3 = r2 & 3;
            int c = pp * 128 + (hh * 4 + t3) * 16 + lmc;   // pi'^-1
            int m = wc * 16 + (lane & 15);
            s1f[i] = (_Float16)S[m * 512 + c];
        } else {                       // s2f: B-frag of S (k = combos)
            int i2 = i - 4 * 16 * 64 * 8;
            int j = i2 & 7, lane = (i2 >> 3) & 63, c = (i2 >> 9) & 1,
                tt = (i2 >> 10) & 7, wc = i2 >> 13;
            int kc = c * 32 + (lane >> 4) * 8 + j;
            int n = wc * 128 + tt * 16 + (lane & 15);
            s2f[i2] = (_Float16)S[kc * 512 + n];
        }
        return;
    }
    power_64(S, tau_g);
}

// ---------------- MEGA: per-block 8 rows end-to-end ----------------------------
// 256 threads, 4 waves. Wave wp owns a column slice per phase.
// G1: H1[8][1024] = relu(X8 @ W1 + b1)  (wave: cols wp*256.., 16 frags)
// G2: H2[8][1024] = relu(H1 @ W2 + b2)  (wave: cols wp*256.., 16 frags, K=1024)
// G3: acc3[8]     =      H2 @ W3        (wave: cols wp*128.., 8 frags,  K=1024)
// pdhg: R16 body; z = relu(acc3 + b3) in-register (frag/lane layout matches).
// A-frags always read LDS row lm&7 (rows 8-15 of MFMA out = live duplicates;
// q>=2 lanes consume the dup rows exactly as pdhg expects: qa=q&1).
__global__ __launch_bounds__(256, 1) void mega(
    const float* __restrict__ X,
    const _Float16* __restrict__ W1t, const float* __restrict__ b1,
    const _Float16* __restrict__ W2t, const float* __restrict__ b2,
    const _Float16* __restrict__ W3t, const float* __restrict__ b3,
    const _Float16* __restrict__ s1f, const _Float16* __restrict__ s2f,
    const float* __restrict__ tau_p, float* __restrict__ out) {
    __shared__ __align__(16) char smem[34304];
    _Float16* H1 = (_Float16*)smem;             // [8][H1S] halves (16512 B)
    _Float16* H2 = (_Float16*)(smem + 16512);   // [8][H1S] halves (16512 B)
    _Float16* X8 = (_Float16*)(smem + 33024);   // [8][72] halves (1152 B)
    // pdhg overlay (H1 region is dead after G2):
    _Float16* xb_d = (_Float16*)smem;               // 8*XBS*2 = 8320 B
    _Float16* yl_d = (_Float16*)(smem + 8320);      // 8*YLS*2 = 1152 B
    float (*red)[4] = (float(*)[4])(smem + 9472);   // 128 B

    int tid = threadIdx.x;
    int wp = tid >> 6;                 // wave
    int l = tid & 63, lm = l & 15, q = l >> 4;
    int lq = lm & 7;                   // LDS A-frag row (broadcast pairs)
    int qa = q & 1, h = q >> 1;
    int b0 = blockIdx.x * 8;

    // ---- stage X8: 8 rows x 64, fp32 -> f16 (RTN, same as old prep cast)
    if (tid < 128) {
        int r = tid >> 4, c = (tid & 15) * 4;
        floatx4 v = *(const floatx4*)&X[(size_t)(b0 + r) * 64 + c];
        fp16x4 hh = {(__fp16)v.x, (__fp16)v.y, (__fp16)v.z, (__fp16)v.w};
        *(fp16x4*)&X8[r * 72 + c] = hh;
    }
    __syncthreads();

    // ================= G1: 16 col frags per wave, K=64 ========================
    {
        floatx4 acc1[16] = {};
#pragma unroll
        for (int kk = 0; kk < 2; kk++) {
            half8 a = *(const half8*)&X8[lq * 72 + kk * 32 + q * 8];
#pragma unroll
            for (int u = 0; u < 16; u++) {
                int col = wp * 256 + u * 16 + lm;
                half8 b = *(const half8*)&W1t[(size_t)col * 64 + kk * 32 + q * 8];
                acc1[u] = __builtin_amdgcn_mfma_f32_16x16x32_f16(a, b, acc1[u], 0, 0, 0);
            }
        }
        if (q < 2) {
#pragma unroll
            for (int u = 0; u < 16; u++) {
                int col = wp * 256 + u * 16 + lm;
                float bv = b1[col];
#pragma unroll
                for (int v = 0; v < 4; v++)
                    H1[(q * 4 + v) * H1S + col] = (_Float16)fmaxf(acc1[u][v] + bv, 0.f);
            }
        }
    }
    __syncthreads();

    // ================= G2: 16 col frags per wave, K=1024 ======================
    {
        floatx4 acc2h[16] = {};
        half8 B2[16];
#pragma unroll
        for (int u = 0; u < 16; u++)
            B2[u] = *(const half8*)&W2t[(size_t)(wp * 256 + u * 16 + lm) * 1024 + q * 8];
        half8 a_cur = *(const half8*)&H1[lq * H1S + q * 8];
#pragma unroll 1
        for (int k0 = 0; k0 < 1024; k0 += 32) {
            int knx = (k0 + 32) & 1023;
            half8 a_nxt = *(const half8*)&H1[lq * H1S + knx + q * 8];
#pragma unroll
            for (int u = 0; u < 16; u++) {
                half8 bn = *(const half8*)&W2t[(size_t)(wp * 256 + u * 16 + lm) * 1024 + knx + q * 8];
                acc2h[u] = __builtin_amdgcn_mfma_f32_16x16x32_f16(a_cur, B2[u], acc2h[u], 0, 0, 0);
                B2[u] = bn;
            }
            a_cur = a_nxt;
        }
        __syncthreads();   // H1 reads complete everywhere (before H2 write? H2 is
                           // a different region; this barrier orders H1-death for overlay)
        if (q < 2) {
#pragma unroll
            for (int u = 0; u < 16; u++) {
                int col = wp * 256 + u * 16 + lm;
                float bv = b2[col];
#pragma unroll
                for (int v = 0; v < 4; v++)
                    H2[(q * 4 + v) * H1S + col] = (_Float16)fmaxf(acc2h[u][v] + bv, 0.f);
            }
        }
    }
    __syncthreads();

    // ================= G3: 8 col frags per wave (cols wp*128..), K=1024 =======
    floatx4 acc3[8] = {};
    {
        half8 B3[8];
#pragma unroll
        for (int u = 0; u < 8; u++)
            B3[u] = *(const half8*)&W3t[(size_t)(wp * 128 + u * 16 + lm) * 1024 + q * 8];
        half8 a_cur = *(const half8*)&H2[lq * H1S + q * 8];
#pragma unroll 1
        for (int k0 = 0; k0 < 1024; k0 += 32) {
            int knx = (k0 + 32) & 1023;
            half8 a_nxt = *(const half8*)&H2[lq * H1S + knx + q * 8];
#pragma unroll
            for (int u = 0; u < 8; u++) {
                half8 bn = *(const half8*)&W3t[(size_t)(wp * 128 + u * 16 + lm) * 1024 + knx + q * 8];
                acc3[u] = __builtin_amdgcn_mfma_f32_16x16x32_f16(a_cur, B3[u], acc3[u], 0, 0, 0);
                B3[u] = bn;
            }
            a_cur = a_nxt;
        }
    }
    __syncthreads();   // all H1/H2 traffic done; overlay region free

    // ================= pdhg phase (R16 body, z from acc3) =====================
    half8 s1[16], s2[8][2];
#pragma unroll
    for (int k = 0; k < 16; k++)
        s1[k] = *(const half8*)&s1f[((wp * 16 + k) * 64 + l) * 8];
#pragma unroll
    for (int u = 0; u < 8; u++)
#pragma unroll
        for (int c = 0; c < 2; c++)
            s2[u][c] = *(const half8*)&s2f[(((wp * 8 + u) * 2 + c) * 64 + l) * 8];

    floatx4 z4[4], tz4[4], x4[4], xb4[4], yh4[4], d4[4];
    floatx4 ylo = {}, Bc;
    floatx4 a1p[4] = {};
    floatx4 acc2[8] = {};
    const floatx4 zero4 = {0.f, 0.f, 0.f, 0.f};
    float tau = tau_p[0];
    float sig = tau;

#pragma unroll
    for (int v = 0; v < 4; v++)
        Bc[v] = X[(size_t)(b0 + qa * 4 + v) * 64 + wp * 16 + lm];
#pragma unroll
    for (int t = 0; t < 4; t++) {
        int col = wp * 128 + (h * 4 + t) * 16 + lm;
        float bv = b3[col];
#pragma unroll
        for (int v = 0; v < 4; v++) {
            float zz = fmaxf(acc3[h * 4 + t][v] + bv, 0.f);   // == Zb value
            z4[t][v] = zz;
            tz4[t][v] = tau - zz;
        }
        x4[t] = zero4; xb4[t] = zero4; yh4[t] = zero4;
    }
    {
        half8 hz = {0, 0, 0, 0, 0, 0, 0, 0};
        for (int i = tid; i < (8 * XBS) / 8; i += 256)
            *(half8*)&xb_d[i * 8] = hz;
        for (int i = tid; i < 8 * YLS; i += 256)
            yl_d[i] = (_Float16)0.f;
    }
    __syncthreads();

#pragma unroll 1
    for (int it = 0; it < NITERS; ++it) {
        // ---- Kx (delta accumulated): a1p += dxbar @ S^T, storage in pi'-order
#pragma unroll
        for (int k = 0; k < 16; k++) {
            half8 ad = *(const half8*)&xb_d[lq * XBS + k * 32 + q * 8];
            a1p[k & 3] = __builtin_amdgcn_mfma_f32_16x16x32_f16(ad, s1[k], a1p[k & 3], 0, 0, 0);
        }
        floatx4 a1 = (a1p[0] + a1p[1]) + (a1p[2] + a1p[3]);
        // ---- y_lo update (rows qa*4+v, combo wp*16+lm); q>=2 lanes duplicate
        floatx4 yv = __builtin_elementwise_max(ylo + sig * (a1 - Bc), zero4);
        floatx4 dy = yv - ylo;
        ylo = yv;
        if (q < 2) {
#pragma unroll
            for (int v = 0; v < 4; v++)
                yl_d[(q * 4 + v) * YLS + wp * 16 + lm] = (_Float16)dy[v];
        }
        __syncthreads();   // [A]
        // ---- KTy (delta accumulated): acc2 += dy @ S
        half8 a2d[2];
#pragma unroll
        for (int c = 0; c < 2; c++)
            a2d[c] = *(const half8*)&yl_d[lq * YLS + c * 32 + q * 8];
#pragma unroll
        for (int u = 0; u < 8; u++)
#pragma unroll
            for (int c = 0; c < 2; c++)
                acc2[u] = __builtin_amdgcn_mfma_f32_16x16x32_f16(a2d[c], s2[u][c], acc2[u], 0, 0, 0);
        // ---- elementwise: all lanes real (h selects tt group)
        floatx4 pn = {};
#pragma unroll
        for (int t = 0; t < 4; t++) {
            floatx4 accs = h ? acc2[t + 4] : acc2[t];
            yh4[t] = __builtin_elementwise_max(yh4[t] - sig * xb4[t], zero4);
            floatx4 kty = accs - yh4[t];
            floatx4 dd = (x4[t] - tau * kty) + tz4[t];
            d4[t] = dd;
            pn += dd * dd;
        }
        // ---- row-norm reduce: 16 lanes (DPP) + q-partner (xor32) + 4 waves (LDS)
#pragma unroll
        for (int v = 0; v < 4; v++) pn[v] = sum16(pn[v]);
#pragma unroll
        for (int v = 0; v < 4; v++) pn[v] += __shfl_xor(pn[v], 32, 64);
        if (lm == 0 && q < 2) {
#pragma unroll
            for (int v = 0; v < 4; v++) red[q * 4 + v][wp] = pn[v];
        }
        __syncthreads();   // [B]
        floatx4 sv;
#pragma unroll
        for (int v = 0; v < 4; v++) {
            floatx4 rr = *(const floatx4*)&red[qa * 4 + v][0];
            float n2 = (rr.x + rr.y) + (rr.z + rr.w);
            sv[v] = fmaxf(1.f - tau * rsqrtf(fmaxf(n2, 1e-24f)), 0.f);
        }
#pragma unroll
        for (int t = 0; t < 4; t++) {
            floatx4 xn = z4[t] + sv * d4[t];
            floatx4 xbn = 2.f * xn - x4[t];
            d4[t] = xbn - xb4[t];   // reuse d4 as delta
            x4[t] = xn;
            xb4[t] = xbn;
        }
        // ---- write delta-xbar f16 at pi'(row, wp, h, lm, t): contiguous fp16x4
#pragma unroll
        for (int v = 0; v < 4; v++) {
            fp16x2 p0 = __builtin_amdgcn_cvt_pkrtz(d4[0][v], d4[1][v]);
            fp16x2 p1 = __builtin_amdgcn_cvt_pkrtz(d4[2][v], d4[3][v]);
            fp16x4 hd = __builtin_shufflevector(p0, p1, 0, 1, 2, 3);
            *(fp16x4*)&xb_d[(qa * 4 + v) * XBS + wp * 128 + h * 64 + lm * 4] = hd;
        }
        __syncthreads();   // [C]
    }
#pragma unroll
    for (int t = 0; t < 4; t++)
#pragma unroll
        for (int v = 0; v < 4; v++)
            out[(size_t)(b0 + qa * 4 + v) * 512 + wp * 128 + (h * 4 + t) * 16 + lm] = x4[t][v];
}

// ---------------------------------------------------------------------------
extern "C" void kernel_launch(void* const* d_in, const int* in_sizes, int n_in,
                              void* d_out, int out_size, void* d_ws, size_t ws_size,
                              hipStream_t stream) {
    const float* X  = (const float*)d_in[0];
    const float* W1 = (const float*)d_in[1];
    const float* b1 = (const float*)d_in[2];
    const float* W2 = (const float*)d_in[3];
    const float* b2 = (const float*)d_in[4];
    const float* W3 = (const float*)d_in[5];
    const float* b3 = (const float*)d_in[6];
    const float* S  = (const float*)d_in[7];
    float* out = (float*)d_out;

    char* ws = (char*)d_ws;
    size_t off = 0;
    auto alloc = [&](size_t bytes) {
        void* p = ws + off;
        off += (bytes + 255) & ~(size_t)255;
        return p;
    };
    _Float16* W1t = (_Float16*)alloc((size_t)64 * 1024 * 2);
    _Float16* W2t = (_Float16*)alloc((size_t)1024 * 1024 * 2);
    _Float16* W3t = (_Float16*)alloc((size_t)1024 * 512 * 2);
    _Float16* s1f = (_Float16*)alloc((size_t)4 * 16 * 64 * 8 * 2);
    _Float16* s2f = (_Float16*)alloc((size_t)4 * 8 * 2 * 64 * 8 * 2);
    float*    tau = (float*)alloc(256);

    hipLaunchKernelGGL(prep, dim3(1857), dim3(256), 0, stream,
                       W1, W1t, W2, W2t, W3, W3t, S, s1f, s2f, tau);
    hipLaunchKernelGGL(mega, dim3(BATCH / 8), dim3(256), 0, stream,
                       X, W1t, b1, W2t, b2, W3t, b3, s1f, s2f, tau, out);
}

// Round 10
// 233.336 us; speedup vs baseline: 1.1987x; 1.1987x over previous
//
#include <hip/hip_runtime.h>

// ---------------------------------------------------------------------------
// MatchNet: 3-layer MLP (relu after every layer) -> batched PDHG LP solve.
// Shapes: X[2048,64], W1[64,1024], W2[1024,1024], W3[1024,512], S[64,512].
// Output: x [2048,512] fp32.
//
// R25: VERBATIM RETRY of R24 (R24 failed with "container failed twice", the
// same opaque infra signature as R21 -- but unlike R21 this kernel has no
// spin barriers / no hang path; full index audit vs the passing R23 found
// no OOB. Hypothesis: infra flake. Decision rule: pass -> R24 theory stands;
// fail again -> real platform issue, revert to R19 next round.)
//
// R24: R23 megakernel + FRAG-PACKED WEIGHTS.
// R23 post-mortem: mega = 193us = 92 (pdhg) + ~100 (MLP). Cause measured:
// strided direct B-frag loads (col stride 2KB) touch 64 separate 64B lines
// per 1KB wave-load = 4x L2 line amplification on ~790MB of per-block weight
// re-reads. Fix: prep packs W1/W2/W3 into MFMA B-frag order (same trick as
// s1f/s2f) -> every frag load is contiguous 1KB/wave; each k-step streams a
// contiguous 64KB slab per block. Identical values & accumulation order ->
// bit-identical output. pdhg phase byte-identical to R16/R19/R23.
// ---------------------------------------------------------------------------

typedef _Float16 half8 __attribute__((ext_vector_type(8)));
typedef __fp16 fp16x2 __attribute__((ext_vector_type(2)));
typedef __fp16 fp16x4 __attribute__((ext_vector_type(4)));
typedef float floatx4 __attribute__((ext_vector_type(4)));

#define BATCH 2048
#define NITERS 60
#define XBS 520   // delta-xbar LDS row stride in halves
#define YLS 72    // delta-ylo  LDS row stride in halves
#define H1S 1032  // H1/H2 LDS row stride in halves

// ---- cross-lane sums: DPP (VALU pipe) within 16-lane rows ----
template <int CTRL>
__device__ __forceinline__ float dpp_addf(float x) {
    int y = __builtin_amdgcn_update_dpp(0, __builtin_bit_cast(int, x), CTRL, 0xf, 0xf, true);
    return x + __builtin_bit_cast(float, y);
}
__device__ __forceinline__ float sum16(float x) {
    x = dpp_addf<0xB1>(x);    // quad_perm(1,0,3,2): xor 1
    x = dpp_addf<0x4E>(x);    // quad_perm(2,3,0,1): xor 2
    x = dpp_addf<0x124>(x);   // row_ror:4
    x = dpp_addf<0x128>(x);   // row_ror:8 -> full 16-lane sum in all lanes
    return x;
}
__device__ __forceinline__ float sum64(float x) {
    x = sum16(x);
    x += __builtin_bit_cast(float, __builtin_amdgcn_ds_swizzle(__builtin_bit_cast(int, x), 0x401F)); // xor16
    x += __shfl_xor(x, 32, 64);   // cross-half combine
    return x;
}

// ---------------- 64-dim power iteration for tau (one 256-thread block) --------
// Exact reduction of the reference 512-dim recursion: w_k = S v_k;
//   n_k = sqrt(w'Gw + 2|w|^2 + 1);  w_{k+1} = (Gw + w)/n_k;
//   w_0[i] = rowcount_i / sqrt(512);  L = sqrt(|w_30|^2 + 1);  tau = 0.9/L.
__device__ void power_64(const float* __restrict__ S, float* __restrict__ tau_g) {
    __shared__ unsigned long long rowm[64][8];   // row bitmasks of S
    __shared__ float G[64][65];                  // Gram, +1 pad (conflict-free)
    __shared__ float wl[64], pg[4][64];
    int t = threadIdx.x, wv = t >> 6, ln = t & 63;
    for (int rr = 0; rr < 16; rr++) {
        int r = wv * 16 + rr;
        float v[8];
#pragma unroll
        for (int e = 0; e < 8; e++) v[e] = S[r * 512 + e * 64 + ln];
#pragma unroll
        for (int e = 0; e < 8; e++) {
            unsigned long long m = __ballot(v[e] != 0.f);
            if (ln == 0) rowm[r][e] = m;
        }
    }
    __syncthreads();
    for (int k = 0; k < 16; k++) {
        int idx = t * 16 + k;
        int i = idx >> 6, j = idx & 63;
        int cnt = 0;
#pragma unroll
        for (int e = 0; e < 8; e++) cnt += __popcll(rowm[i][e] & rowm[j][e]);
        G[i][j] = (float)cnt;
    }
    if (wv == 0) {   // w0 = S v0 = rowcount/sqrt(512)
        int cnt = 0;
#pragma unroll
        for (int e = 0; e < 8; e++) cnt += __popcll(rowm[ln][e]);
        wl[ln] = (float)cnt * 0.044194173824159216f;
    }
    __syncthreads();
    for (int s = 0; s < 30; s++) {
        float a = 0.f;
#pragma unroll
        for (int jj = 0; jj < 16; jj++) {
            int j = wv * 16 + jj;
            a += G[ln][j] * wl[j];
        }
        pg[wv][ln] = a;
        __syncthreads();
        if (wv == 0) {
            float g = (pg[0][ln] + pg[1][ln]) + (pg[2][ln] + pg[3][ln]);  // (Gw)[ln]
            float wi = wl[ln];
            float s1 = sum64(wi * g);    // w'Gw
            float s2 = sum64(wi * wi);   // |w|^2
            float n = sqrtf(s1 + 2.f * s2 + 1.f);
            wl[ln] = (g + wi) / n;
        }
        __syncthreads();
    }
    if (wv == 0) {
        float wi = wl[ln];
        float s2 = sum64(wi * wi);
        if (ln == 0) tau_g[0] = 0.9f / sqrtf(s2 + 1.f);
    }
}

// ---------------- prep: frag-pack W1/W2/W3, S frags, power_64 ------------------
// Packed layouts (j=half index 0..7, lane, cf=col-frag, ks=k-step):
//  w1f[((kk*64 + cf)*64 + lane)*8 + j] = (f16) W1[kk*32+(lane>>4)*8+j][colof(cf,lane)]
//  w2f[((ks*64 + cf)*64 + lane)*8 + j] = (f16) W2[ks*32+(lane>>4)*8+j][colof(cf,lane)]
//  w3f[((ks*32 + cf)*64 + lane)*8 + j] = (f16) W3[ks*32+(lane>>4)*8+j][colof3(cf,lane)]
// colof(cf,lane) = (cf>>4)*256 + (cf&15)*16 + (lane&15)   (cf in [0,64))
// colof3(cf,lane) = (cf>>3)*128 + (cf&7)*16 + (lane&15)   (cf in [0,32))
__global__ __launch_bounds__(256) void prep(
    const float* __restrict__ W1, _Float16* __restrict__ w1f,
    const float* __restrict__ W2, _Float16* __restrict__ w2f,
    const float* __restrict__ W3, _Float16* __restrict__ w3f,
    const float* __restrict__ S, _Float16* __restrict__ s1f,
    _Float16* __restrict__ s2f, float* __restrict__ tau_g) {
    int tid = threadIdx.x;
    int bid = blockIdx.x;
    if (bid < 32) {            // w1f: 65536 halves, 8 per thread
        int i0 = (bid * 256 + tid) * 8;
        int lane = (i0 >> 3) & 63, cf = (i0 >> 9) & 63, kk = i0 >> 15;
        int col = (cf >> 4) * 256 + (cf & 15) * 16 + (lane & 15);
        int kb = kk * 32 + ((lane >> 4) << 3);
        half8 vv;
#pragma unroll
        for (int j = 0; j < 8; j++)
            vv[j] = (_Float16)W1[(size_t)(kb + j) * 1024 + col];
        *(half8*)&w1f[i0] = vv;
        return;
    }
    if (bid < 544) {           // w2f: 1048576 halves
        int i0 = ((bid - 32) * 256 + tid) * 8;
        int lane = (i0 >> 3) & 63, cf = (i0 >> 9) & 63, ks = i0 >> 15;
        int col = (cf >> 4) * 256 + (cf & 15) * 16 + (lane & 15);
        int kb = ks * 32 + ((lane >> 4) << 3);
        half8 vv;
#pragma unroll
        for (int j = 0; j < 8; j++)
            vv[j] = (_Float16)W2[(size_t)(kb + j) * 1024 + col];
        *(half8*)&w2f[i0] = vv;
        return;
    }
    if (bid < 800) {           // w3f: 524288 halves
        int i0 = ((bid - 544) * 256 + tid) * 8;
        int lane = (i0 >> 3) & 63, cf = (i0 >> 9) & 31, ks = i0 >> 14;
        int col = (cf >> 3) * 128 + (cf & 7) * 16 + (lane & 15);
        int kb = ks * 32 + ((lane >> 4) << 3);
        half8 vv;
#pragma unroll
        for (int j = 0; j < 8; j++)
            vv[j] = (_Float16)W3[(size_t)(kb + j) * 512 + col];
        *(half8*)&w3f[i0] = vv;
        return;
    }
    if (bid < 1056) {          // S frags (unchanged layouts)
        int i = (bid - 800) * 256 + tid;   // 0 .. 65535
        if (i < 4 * 16 * 64 * 8) {     // s1f: B-frag of S^T, k-axis in pi'-order
            int j = i & 7, lane = (i >> 3) & 63, kk = (i >> 9) & 15, wc = i >> 13;
            int pos = kk * 32 + (lane >> 4) * 8 + j;   // storage k position 0..511
            int pp = pos >> 7, r = pos & 127;
            int hh = r >> 6, r2 = r & 63;
            int lmc = r2 >> 2, t3 = r2 & 3;
            int c = pp * 128 + (hh * 4 + t3) * 16 + lmc;   // pi'^-1
            int m = wc * 16 + (lane & 15);
            s1f[i] = (_Float16)S[m * 512 + c];
        } else {                       // s2f: B-frag of S (k = combos)
            int i2 = i - 4 * 16 * 64 * 8;
            int j = i2 & 7, lane = (i2 >> 3) & 63, c = (i2 >> 9) & 1,
                tt = (i2 >> 10) & 7, wc = i2 >> 13;
            int kc = c * 32 + (lane >> 4) * 8 + j;
            int n = wc * 128 + tt * 16 + (lane & 15);
            s2f[i2] = (_Float16)S[kc * 512 + n];
        }
        return;
    }
    power_64(S, tau_g);
}

// ---------------- MEGA: per-block 8 rows end-to-end ----------------------------
// 256 threads, 4 waves. Wave wp owns a column slice per phase.
// G1: H1[8][1024] = relu(X8 @ W1 + b1)  (wave: cols wp*256.., 16 frags)
// G2: H2[8][1024] = relu(H1 @ W2 + b2)  (wave: cols wp*256.., 16 frags, K=1024)
// G3: acc3[8]     =      H2 @ W3        (wave: cols wp*128.., 8 frags,  K=1024)
// pdhg: R16 body; z = relu(acc3 + b3) in-register (frag layout matches).
// All B-frags stream CONTIGUOUSLY from packed w1f/w2f/w3f (1KB/wave/frag).
__global__ __launch_bounds__(256, 1) void mega(
    const float* __restrict__ X,
    const _Float16* __restrict__ w1f, const float* __restrict__ b1,
    const _Float16* __restrict__ w2f, const float* __restrict__ b2,
    const _Float16* __restrict__ w3f, const float* __restrict__ b3,
    const _Float16* __restrict__ s1f, const _Float16* __restrict__ s2f,
    const float* __restrict__ tau_p, float* __restrict__ out) {
    __shared__ __align__(16) char smem[34304];
    _Float16* H1 = (_Float16*)smem;             // [8][H1S] halves (16512 B)
    _Float16* H2 = (_Float16*)(smem + 16512);   // [8][H1S] halves (16512 B)
    _Float16* X8 = (_Float16*)(smem + 33024);   // [8][72] halves (1152 B)
    // pdhg overlay (H1 region is dead after G2):
    _Float16* xb_d = (_Float16*)smem;               // 8*XBS*2 = 8320 B
    _Float16* yl_d = (_Float16*)(smem + 8320);      // 8*YLS*2 = 1152 B
    float (*red)[4] = (float(*)[4])(smem + 9472);   // 128 B

    int tid = threadIdx.x;
    int wp = tid >> 6;                 // wave
    int l = tid & 63, lm = l & 15, q = l >> 4;
    int lq = lm & 7;                   // LDS A-frag row (broadcast pairs)
    int qa = q & 1, h = q >> 1;
    int b0 = blockIdx.x * 8;

    // ---- stage X8: 8 rows x 64, fp32 -> f16 (RTN, same as old prep cast)
    if (tid < 128) {
        int r = tid >> 4, c = (tid & 15) * 4;
        floatx4 v = *(const floatx4*)&X[(size_t)(b0 + r) * 64 + c];
        fp16x4 hh = {(__fp16)v.x, (__fp16)v.y, (__fp16)v.z, (__fp16)v.w};
        *(fp16x4*)&X8[r * 72 + c] = hh;
    }
    __syncthreads();

    // ================= G1: 16 col frags per wave, K=64 ========================
    {
        floatx4 acc1[16] = {};
#pragma unroll
        for (int kk = 0; kk < 2; kk++) {
            half8 a = *(const half8*)&X8[lq * 72 + kk * 32 + q * 8];
#pragma unroll
            for (int u = 0; u < 16; u++) {
                half8 b = *(const half8*)&w1f[((kk * 64 + wp * 16 + u) * 64 + l) * 8];
                acc1[u] = __builtin_amdgcn_mfma_f32_16x16x32_f16(a, b, acc1[u], 0, 0, 0);
            }
        }
        if (q < 2) {
#pragma unroll
            for (int u = 0; u < 16; u++) {
                int col = wp * 256 + u * 16 + lm;
                float bv = b1[col];
#pragma unroll
                for (int v = 0; v < 4; v++)
                    H1[(q * 4 + v) * H1S + col] = (_Float16)fmaxf(acc1[u][v] + bv, 0.f);
            }
        }
    }
    __syncthreads();

    // ================= G2: 16 col frags per wave, K=1024 ======================
    {
        floatx4 acc2h[16] = {};
        half8 B2[16];
#pragma unroll
        for (int u = 0; u < 16; u++)
            B2[u] = *(const half8*)&w2f[((0 * 64 + wp * 16 + u) * 64 + l) * 8];
        half8 a_cur = *(const half8*)&H1[lq * H1S + q * 8];
#pragma unroll 1
        for (int ks = 0; ks < 32; ks++) {
            int ksn = (ks + 1) & 31;
            half8 a_nxt = *(const half8*)&H1[lq * H1S + ksn * 32 + q * 8];
#pragma unroll
            for (int u = 0; u < 16; u++) {
                half8 bn = *(const half8*)&w2f[((ksn * 64 + wp * 16 + u) * 64 + l) * 8];
                acc2h[u] = __builtin_amdgcn_mfma_f32_16x16x32_f16(a_cur, B2[u], acc2h[u], 0, 0, 0);
                B2[u] = bn;
            }
            a_cur = a_nxt;
        }
        __syncthreads();
        if (q < 2) {
#pragma unroll
            for (int u = 0; u < 16; u++) {
                int col = wp * 256 + u * 16 + lm;
                float bv = b2[col];
#pragma unroll
                for (int v = 0; v < 4; v++)
                    H2[(q * 4 + v) * H1S + col] = (_Float16)fmaxf(acc2h[u][v] + bv, 0.f);
            }
        }
    }
    __syncthreads();

    // ================= G3: 8 col frags per wave (cols wp*128..), K=1024 =======
    floatx4 acc3[8] = {};
    {
        half8 B3[8];
#pragma unroll
        for (int u = 0; u < 8; u++)
            B3[u] = *(const half8*)&w3f[((0 * 32 + wp * 8 + u) * 64 + l) * 8];
        half8 a_cur = *(const half8*)&H2[lq * H1S + q * 8];
#pragma unroll 1
        for (int ks = 0; ks < 32; ks++) {
            int ksn = (ks + 1) & 31;
            half8 a_nxt = *(const half8*)&H2[lq * H1S + ksn * 32 + q * 8];
#pragma unroll
            for (int u = 0; u < 8; u++) {
                half8 bn = *(const half8*)&w3f[((ksn * 32 + wp * 8 + u) * 64 + l) * 8];
                acc3[u] = __builtin_amdgcn_mfma_f32_16x16x32_f16(a_cur, B3[u], acc3[u], 0, 0, 0);
                B3[u] = bn;
            }
            a_cur = a_nxt;
        }
    }
    __syncthreads();   // all H1/H2 traffic done; overlay region free

    // ================= pdhg phase (R16 body, z from acc3) =====================
    half8 s1[16], s2[8][2];
#pragma unroll
    for (int k = 0; k < 16; k++)
        s1[k] = *(const half8*)&s1f[((wp * 16 + k) * 64 + l) * 8];
#pragma unroll
    for (int u = 0; u < 8; u++)
#pragma unroll
        for (int c = 0; c < 2; c++)
            s2[u][c] = *(const half8*)&s2f[(((wp * 8 + u) * 2 + c) * 64 + l) * 8];

    floatx4 z4[4], tz4[4], x4[4], xb4[4], yh4[4], d4[4];
    floatx4 ylo = {}, Bc;
    floatx4 a1p[4] = {};
    floatx4 acc2[8] = {};
    const floatx4 zero4 = {0.f, 0.f, 0.f, 0.f};
    float tau = tau_p[0];
    float sig = tau;

#pragma unroll
    for (int v = 0; v < 4; v++)
        Bc[v] = X[(size_t)(b0 + qa * 4 + v) * 64 + wp * 16 + lm];
#pragma unroll
    for (int t = 0; t < 4; t++) {
        int col = wp * 128 + (h * 4 + t) * 16 + lm;
        float bv = b3[col];
#pragma unroll
        for (int v = 0; v < 4; v++) {
            float zz = fmaxf(acc3[h * 4 + t][v] + bv, 0.f);   // == Zb value
            z4[t][v] = zz;
            tz4[t][v] = tau - zz;
        }
        x4[t] = zero4; xb4[t] = zero4; yh4[t] = zero4;
    }
    {
        half8 hz = {0, 0, 0, 0, 0, 0, 0, 0};
        for (int i = tid; i < (8 * XBS) / 8; i += 256)
            *(half8*)&xb_d[i * 8] = hz;
        for (int i = tid; i < 8 * YLS; i += 256)
            yl_d[i] = (_Float16)0.f;
    }
    __syncthreads();

#pragma unroll 1
    for (int it = 0; it < NITERS; ++it) {
        // ---- Kx (delta accumulated): a1p += dxbar @ S^T, storage in pi'-order
#pragma unroll
        for (int k = 0; k < 16; k++) {
            half8 ad = *(const half8*)&xb_d[lq * XBS + k * 32 + q * 8];
            a1p[k & 3] = __builtin_amdgcn_mfma_f32_16x16x32_f16(ad, s1[k], a1p[k & 3], 0, 0, 0);
        }
        floatx4 a1 = (a1p[0] + a1p[1]) + (a1p[2] + a1p[3]);
        // ---- y_lo update (rows qa*4+v, combo wp*16+lm); q>=2 lanes duplicate
        floatx4 yv = __builtin_elementwise_max(ylo + sig * (a1 - Bc), zero4);
        floatx4 dy = yv - ylo;
        ylo = yv;
        if (q < 2) {
#pragma unroll
            for (int v = 0; v < 4; v++)
                yl_d[(q * 4 + v) * YLS + wp * 16 + lm] = (_Float16)dy[v];
        }
        __syncthreads();   // [A]
        // ---- KTy (delta accumulated): acc2 += dy @ S
        half8 a2d[2];
#pragma unroll
        for (int c = 0; c < 2; c++)
            a2d[c] = *(const half8*)&yl_d[lq * YLS + c * 32 + q * 8];
#pragma unroll
        for (int u = 0; u < 8; u++)
#pragma unroll
            for (int c = 0; c < 2; c++)
                acc2[u] = __builtin_amdgcn_mfma_f32_16x16x32_f16(a2d[c], s2[u][c], acc2[u], 0, 0, 0);
        // ---- elementwise: all lanes real (h selects tt group)
        floatx4 pn = {};
#pragma unroll
        for (int t = 0; t < 4; t++) {
            floatx4 accs = h ? acc2[t + 4] : acc2[t];
            yh4[t] = __builtin_elementwise_max(yh4[t] - sig * xb4[t], zero4);
            floatx4 kty = accs - yh4[t];
            floatx4 dd = (x4[t] - tau * kty) + tz4[t];
            d4[t] = dd;
            pn += dd * dd;
        }
        // ---- row-norm reduce: 16 lanes (DPP) + q-partner (xor32) + 4 waves (LDS)
#pragma unroll
        for (int v = 0; v < 4; v++) pn[v] = sum16(pn[v]);
#pragma unroll
        for (int v = 0; v < 4; v++) pn[v] += __shfl_xor(pn[v], 32, 64);
        if (lm == 0 && q < 2) {
#pragma unroll
            for (int v = 0; v < 4; v++) red[q * 4 + v][wp] = pn[v];
        }
        __syncthreads();   // [B]
        floatx4 sv;
#pragma unroll
        for (int v = 0; v < 4; v++) {
            floatx4 rr = *(const floatx4*)&red[qa * 4 + v][0];
            float n2 = (rr.x + rr.y) + (rr.z + rr.w);
            sv[v] = fmaxf(1.f - tau * rsqrtf(fmaxf(n2, 1e-24f)), 0.f);
        }
#pragma unroll
        for (int t = 0; t < 4; t++) {
            floatx4 xn = z4[t] + sv * d4[t];
            floatx4 xbn = 2.f * xn - x4[t];
            d4[t] = xbn - xb4[t];   // reuse d4 as delta
            x4[t] = xn;
            xb4[t] = xbn;
        }
        // ---- write delta-xbar f16 at pi'(row, wp, h, lm, t): contiguous fp16x4
#pragma unroll
        for (int v = 0; v < 4; v++) {
            fp16x2 p0 = __builtin_amdgcn_cvt_pkrtz(d4[0][v], d4[1][v]);
            fp16x2 p1 = __builtin_amdgcn_cvt_pkrtz(d4[2][v], d4[3][v]);
            fp16x4 hd = __builtin_shufflevector(p0, p1, 0, 1, 2, 3);
            *(fp16x4*)&xb_d[(qa * 4 + v) * XBS + wp * 128 + h * 64 + lm * 4] = hd;
        }
        __syncthreads();   // [C]
    }
#pragma unroll
    for (int t = 0; t < 4; t++)
#pragma unroll
        for (int v = 0; v < 4; v++)
            out[(size_t)(b0 + qa * 4 + v) * 512 + wp * 128 + (h * 4 + t) * 16 + lm] = x4[t][v];
}

// ---------------------------------------------------------------------------
extern "C" void kernel_launch(void* const* d_in, const int* in_sizes, int n_in,
                              void* d_out, int out_size, void* d_ws, size_t ws_size,
                              hipStream_t stream) {
    const float* X  = (const float*)d_in[0];
    const float* W1 = (const float*)d_in[1];
    const float* b1 = (const float*)d_in[2];
    const float* W2 = (const float*)d_in[3];
    const float* b2 = (const float*)d_in[4];
    const float* W3 = (const float*)d_in[5];
    const float* b3 = (const float*)d_in[6];
    const float* S  = (const float*)d_in[7];
    float* out = (float*)d_out;

    char* ws = (char*)d_ws;
    size_t off = 0;
    auto alloc = [&](size_t bytes) {
        void* p = ws + off;
        off += (bytes + 255) & ~(size_t)255;
        return p;
    };
    _Float16* w1f = (_Float16*)alloc((size_t)65536 * 2);
    _Float16* w2f = (_Float16*)alloc((size_t)1048576 * 2);
    _Float16* w3f = (_Float16*)alloc((size_t)524288 * 2);
    _Float16* s1f = (_Float16*)alloc((size_t)4 * 16 * 64 * 8 * 2);
    _Float16* s2f = (_Float16*)alloc((size_t)4 * 8 * 2 * 64 * 8 * 2);
    float*    tau = (float*)alloc(256);

    hipLaunchKernelGGL(prep, dim3(1057), dim3(256), 0, stream,
                       W1, w1f, W2, w2f, W3, w3f, S, s1f, s2f, tau);
    hipLaunchKernelGGL(mega, dim3(BATCH / 8), dim3(256), 0, stream,
                       X, w1f, b1, w2f, b2, w3f, b3, s1f, s2f, tau, out);
}